// Round 10
// baseline (263.292 us; speedup 1.0000x reference)
//
#include <hip/hip_runtime.h>

// WaveConv3d: B=4, C=32, D=H=W=64, LEVEL=2, m=16.
// Stage 1: s[inp][k][b][c][v16] = (1/8) * WHT3( 2x2x2 sums of 4x4x4 block )
// Stage 2: mixed[k][b][o][v] = sum_i s1*W1 + s2*W2   (per-voxel 32x32 mixing)
// Stage 3: out = (1/8) * invWHT3(mixed) broadcast to 4x4x4 blocks
//
// R10: warm attribution (R9 idempotent-mix delta): k_fwd~70, k_mix~62,
// k_inv~28, gaps~7 of the 166.5us timed total. All kernels at 75-80% of the
// 6.3TB/s ceiling; the rocprof "100us k_fwd / 2.7TB/s" was regime inflation
// (~1.4x). This round: k_mix only -- float2-vectorize the voxel axis
// (512B wave-segments instead of 256B, half the load instructions, same
// outstanding-byte capability per SIMD). k_fwd/k_inv untouched.

#define M3 4096        // 16*16*16 voxels
#define KS 524288      // 4*32*M3  : k-stride in s / mixed
#define IS 4194304     // 8*KS     : input-stride in s

__global__ __launch_bounds__(256) void k_fwd(const float* __restrict__ x1,
                                             const float* __restrict__ x2,
                                             float* __restrict__ s) {
  const int tid = blockIdx.x * 256 + threadIdx.x;   // 2048 blocks
  const int v  = tid & 4095;
  const int bc = tid >> 12;          // 0..127  (b*32+c)
  const int z = v & 15, y = (v >> 4) & 15, x = v >> 8;
  const size_t base = ((((size_t)bc * 64 + 4 * x) * 64 + 4 * y) * 64 + 4 * z);
  // 4 independent address streams: {x1,x2} x {planes dd=0,1 | dd=2,3}
  const float* __restrict__ p10 = x1 + base;
  const float* __restrict__ p11 = x1 + base + 2 * 4096;
  const float* __restrict__ p20 = x2 + base;
  const float* __restrict__ p21 = x2 + base + 2 * 4096;

  float4 a1[2][2], a2[2][2];         // [p][q] float4 partial sums
#pragma unroll
  for (int p = 0; p < 2; ++p)
#pragma unroll
    for (int q = 0; q < 2; ++q) {
      a1[p][q] = make_float4(0.f, 0.f, 0.f, 0.f);
      a2[p][q] = make_float4(0.f, 0.f, 0.f, 0.f);
    }

#pragma unroll
  for (int dp = 0; dp < 2; ++dp) {     // dd within each plane-pair
#pragma unroll
    for (int hh = 0; hh < 4; ++hh) {
      const int off = (dp * 64 + hh) * 64;   // dd*4096 + hh*64
      const float4 f10 = *reinterpret_cast<const float4*>(p10 + off);
      const float4 f20 = *reinterpret_cast<const float4*>(p20 + off);
      const float4 f11 = *reinterpret_cast<const float4*>(p11 + off);
      const float4 f21 = *reinterpret_cast<const float4*>(p21 + off);
      const int q = hh >> 1;
      a1[0][q].x += f10.x; a1[0][q].y += f10.y; a1[0][q].z += f10.z; a1[0][q].w += f10.w;
      a1[1][q].x += f11.x; a1[1][q].y += f11.y; a1[1][q].z += f11.z; a1[1][q].w += f11.w;
      a2[0][q].x += f20.x; a2[0][q].y += f20.y; a2[0][q].z += f20.z; a2[0][q].w += f20.w;
      a2[1][q].x += f21.x; a2[1][q].y += f21.y; a2[1][q].z += f21.z; a2[1][q].w += f21.w;
    }
  }

#pragma unroll
  for (int inp = 0; inp < 2; ++inp) {
    float4 (*A)[2] = inp ? a2 : a1;
    const float b0 = A[0][0].x + A[0][0].y, b1 = A[0][0].z + A[0][0].w;
    const float b2 = A[0][1].x + A[0][1].y, b3 = A[0][1].z + A[0][1].w;
    const float b4 = A[1][0].x + A[1][0].y, b5 = A[1][0].z + A[1][0].w;
    const float b6 = A[1][1].x + A[1][1].y, b7 = A[1][1].z + A[1][1].w;
    const float t0 = b0 + b1, t1 = b0 - b1, t2 = b2 + b3, t3 = b2 - b3;
    const float t4 = b4 + b5, t5 = b4 - b5, t6 = b6 + b7, t7 = b6 - b7;
    const float u0 = t0 + t2, u2 = t0 - t2, u1 = t1 + t3, u3 = t1 - t3;
    const float u4 = t4 + t6, u6 = t4 - t6, u5 = t5 + t7, u7 = t5 - t7;
    float* o = s + (size_t)inp * IS + (size_t)bc * M3 + v;
    o[0 * KS] = 0.125f * (u0 + u4);
    o[4 * KS] = 0.125f * (u0 - u4);
    o[1 * KS] = 0.125f * (u1 + u5);
    o[5 * KS] = 0.125f * (u1 - u5);
    o[2 * KS] = 0.125f * (u2 + u6);
    o[6 * KS] = 0.125f * (u2 - u6);
    o[3 * KS] = 0.125f * (u3 + u7);
    o[7 * KS] = 0.125f * (u3 - u7);
  }
}

// R10 k_mix: float2-vectorized voxel axis. 256 blocks: k(8) x og(4) x
// v2blk(8); k = bid&7 keeps the XCD pinning (each k's 2MB s-slice L2-hot).
// Each thread: 2 voxels x 8 oo x 4 b, acc = float2[4][8] (64 VGPR).
// Wave load segments: 512B (vs 256B scalar), half the load instructions.
__global__ __launch_bounds__(256, 1) void k_mix(const float* __restrict__ W1,
                                                const float* __restrict__ W2,
                                                const float* __restrict__ s,
                                                float* __restrict__ mixed) {
  const int bid  = blockIdx.x;
  const int k    = bid & 7;
  const int rest = bid >> 3;       // og(4) x v2blk(8)
  const int og   = rest & 3;
  const int v2b  = rest >> 2;
  const int v = (v2b * 256 + threadIdx.x) * 2;   // even voxel index
  const float* pW1 = W1 + ((size_t)k * 1024 + og * 8) * M3 + v;
  const float* pW2 = W2 + ((size_t)k * 1024 + og * 8) * M3 + v;
  const float* ps  = s + (size_t)k * KS + v;
  float2 acc[4][8];
#pragma unroll
  for (int b = 0; b < 4; ++b)
#pragma unroll
    for (int oo = 0; oo < 8; ++oo) acc[b][oo] = make_float2(0.f, 0.f);
#pragma unroll 2
  for (int i = 0; i < 32; ++i) {
    float2 s1b[4], s2b[4];
#pragma unroll
    for (int b = 0; b < 4; ++b) {
      s1b[b] = *reinterpret_cast<const float2*>(ps + (size_t)(b * 32 + i) * M3);
      s2b[b] = *reinterpret_cast<const float2*>(ps + (size_t)IS + (size_t)(b * 32 + i) * M3);
    }
#pragma unroll
    for (int oo = 0; oo < 8; ++oo) {
      const float2 w1 = *reinterpret_cast<const float2*>(pW1 + (size_t)(i * 32 + oo) * M3);
      const float2 w2 = *reinterpret_cast<const float2*>(pW2 + (size_t)(i * 32 + oo) * M3);
#pragma unroll
      for (int b = 0; b < 4; ++b) {
        acc[b][oo].x += s1b[b].x * w1.x + s2b[b].x * w2.x;
        acc[b][oo].y += s1b[b].y * w1.y + s2b[b].y * w2.y;
      }
    }
  }
  float* pm = mixed + (size_t)k * KS + (size_t)og * 8 * M3 + v;
#pragma unroll
  for (int b = 0; b < 4; ++b)
#pragma unroll
    for (int oo = 0; oo < 8; ++oo)
      *reinterpret_cast<float2*>(pm + (size_t)b * (32 * M3) + (size_t)oo * M3) = acc[b][oo];
}

__global__ __launch_bounds__(256) void k_inv(const float* __restrict__ mixed,
                                             float* __restrict__ out) {
  const int tid = blockIdx.x * 256 + threadIdx.x;  // 4*32*4096 threads
  const int v = tid & 4095;
  const int o = (tid >> 12) & 31;
  const int b = tid >> 17;
  const float* pm = mixed + (size_t)(b * 32 + o) * M3 + v;
  const float m0 = pm[0 * (size_t)KS], m1 = pm[1 * (size_t)KS];
  const float m2 = pm[2 * (size_t)KS], m3 = pm[3 * (size_t)KS];
  const float m4 = pm[4 * (size_t)KS], m5 = pm[5 * (size_t)KS];
  const float m6 = pm[6 * (size_t)KS], m7 = pm[7 * (size_t)KS];
  const float t0 = m0 + m1, t1 = m0 - m1, t2 = m2 + m3, t3 = m2 - m3;
  const float t4 = m4 + m5, t5 = m4 - m5, t6 = m6 + m7, t7 = m6 - m7;
  const float u0 = t0 + t2, u2 = t0 - t2, u1 = t1 + t3, u3 = t1 - t3;
  const float u4 = t4 + t6, u6 = t4 - t6, u5 = t5 + t7, u7 = t5 - t7;
  float w[2][2][2];  // w[p][q][r], m = p*4+q*2+r, includes the 1/8
  w[0][0][0] = 0.125f * (u0 + u4);
  w[1][0][0] = 0.125f * (u0 - u4);
  w[0][0][1] = 0.125f * (u1 + u5);
  w[1][0][1] = 0.125f * (u1 - u5);
  w[0][1][0] = 0.125f * (u2 + u6);
  w[1][1][0] = 0.125f * (u2 - u6);
  w[0][1][1] = 0.125f * (u3 + u7);
  w[1][1][1] = 0.125f * (u3 - u7);
  const int z = v & 15, y = (v >> 4) & 15, x = v >> 8;
  float* base =
      out + ((((size_t)(b * 32 + o) * 64 + 4 * x) * 64 + 4 * y) * 64 + 4 * z);
#pragma unroll
  for (int dd = 0; dd < 4; ++dd) {
    const int p = dd >> 1;
#pragma unroll
    for (int hh = 0; hh < 4; ++hh) {
      const int q = hh >> 1;
      const float lo = w[p][q][0], hi = w[p][q][1];
      float4 f;
      f.x = lo; f.y = lo; f.z = hi; f.w = hi;
      *reinterpret_cast<float4*>(base + (dd * 64 + hh) * 64) = f;
    }
  }
}

extern "C" void kernel_launch(void* const* d_in, const int* in_sizes, int n_in,
                              void* d_out, int out_size, void* d_ws, size_t ws_size,
                              hipStream_t stream) {
  const float* x1 = (const float*)d_in[0];
  const float* x2 = (const float*)d_in[1];
  const float* W1 = (const float*)d_in[2];
  const float* W2 = (const float*)d_in[3];
  float* out = (float*)d_out;
  float* s     = (float*)d_ws;             // 2*IS floats = 32 MiB
  float* mixed = s + 2 * (size_t)IS;       // IS floats   = 16 MiB
  k_fwd<<<2048, 256, 0, stream>>>(x1, x2, s);
  k_mix<<<256, 256, 0, stream>>>(W1, W2, s, mixed);
  k_inv<<<2048, 256, 0, stream>>>(mixed, out);
}

// Round 12
// 171.547 us; speedup vs baseline: 1.5348x; 1.5348x over previous
//
#include <hip/hip_runtime.h>

// WaveConv3d: B=4, C=32, D=H=W=64, LEVEL=2, m=16.
// Stage 1: s[inp][k][b][c][v16] = (1/8) * WHT3( 2x2x2 sums of 4x4x4 block )
// Stage 2: mixed[k][b][o][v] = sum_i s1*W1 + s2*W2   (per-voxel 32x32 mixing)
// Stage 3: out = (1/8) * invWHT3(mixed) broadcast to 4x4x4 blocks
//
// R12: R11 minus the duplicated k_fwd launch. R11's post-timing divergence
// appeared only with the same-buffer-written-twice graph (pre-timing check
// passed, math verified identical to R7); rule: no duplicated writers.
// Timed total resolves the remaining attribution ambiguity:
//   ~167us -> k_fwd unchanged (~46) and k_inv ~53 (2.2x roofline; next lever)
//   ~152us -> k_fwd improved (~62 vs 77) and k_inv ~22 (near roofline)

#define M3 4096        // 16*16*16 voxels
#define KS 524288      // 4*32*M3  : k-stride in s / mixed
#define IS 4194304     // 8*KS     : input-stride in s

// z-pair k_fwd: 2 voxels/thread, float4-PAIR loads (32B/lane), float2 stores
// (512B wave segments on the 8xKS-strided s-writes). 1024 blocks x 256.
__global__ __launch_bounds__(256) void k_fwd(const float* __restrict__ x1,
                                             const float* __restrict__ x2,
                                             float* __restrict__ s) {
  const int tid = blockIdx.x * 256 + threadIdx.x;   // 1024 blocks
  const int v2 = tid & 2047;          // voxel-pair index within bc
  const int bc = tid >> 11;           // 0..127  (b*32+c)
  const int zp = v2 & 7, y = (v2 >> 3) & 15, x = v2 >> 7;
  const size_t base =
      ((((size_t)bc * 64 + 4 * x) * 64 + 4 * y) * 64 + 8 * zp);
  const float* __restrict__ P1 = x1 + base;
  const float* __restrict__ P2 = x2 + base;

  // acc[inp][vox][p][q]; voxel0 = z=2zp (floats +0..3), voxel1 = z=2zp+1 (+4..7)
  float4 a1v0[2][2], a1v1[2][2], a2v0[2][2], a2v1[2][2];
#pragma unroll
  for (int p = 0; p < 2; ++p)
#pragma unroll
    for (int q = 0; q < 2; ++q) {
      a1v0[p][q] = make_float4(0.f, 0.f, 0.f, 0.f);
      a1v1[p][q] = make_float4(0.f, 0.f, 0.f, 0.f);
      a2v0[p][q] = make_float4(0.f, 0.f, 0.f, 0.f);
      a2v1[p][q] = make_float4(0.f, 0.f, 0.f, 0.f);
    }

#pragma unroll
  for (int dd = 0; dd < 4; ++dd) {
#pragma unroll
    for (int hh = 0; hh < 4; ++hh) {
      const int off = (dd * 64 + hh) * 64;
      const float4 f1a = *reinterpret_cast<const float4*>(P1 + off);
      const float4 f1b = *reinterpret_cast<const float4*>(P1 + off + 4);
      const float4 f2a = *reinterpret_cast<const float4*>(P2 + off);
      const float4 f2b = *reinterpret_cast<const float4*>(P2 + off + 4);
      const int p = dd >> 1, q = hh >> 1;
      a1v0[p][q].x += f1a.x; a1v0[p][q].y += f1a.y; a1v0[p][q].z += f1a.z; a1v0[p][q].w += f1a.w;
      a1v1[p][q].x += f1b.x; a1v1[p][q].y += f1b.y; a1v1[p][q].z += f1b.z; a1v1[p][q].w += f1b.w;
      a2v0[p][q].x += f2a.x; a2v0[p][q].y += f2a.y; a2v0[p][q].z += f2a.z; a2v0[p][q].w += f2a.w;
      a2v1[p][q].x += f2b.x; a2v1[p][q].y += f2b.y; a2v1[p][q].z += f2b.z; a2v1[p][q].w += f2b.w;
    }
  }

  const int v = x * 256 + y * 16 + 2 * zp;   // even voxel index
#pragma unroll
  for (int inp = 0; inp < 2; ++inp) {
    float4 (*A0)[2] = inp ? a2v0 : a1v0;
    float4 (*A1)[2] = inp ? a2v1 : a1v1;
    float sk0[8], sk1[8];
#pragma unroll
    for (int vox = 0; vox < 2; ++vox) {
      float4 (*A)[2] = vox ? A1 : A0;
      float* sk = vox ? sk1 : sk0;
      const float b0 = A[0][0].x + A[0][0].y, b1 = A[0][0].z + A[0][0].w;
      const float b2 = A[0][1].x + A[0][1].y, b3 = A[0][1].z + A[0][1].w;
      const float b4 = A[1][0].x + A[1][0].y, b5 = A[1][0].z + A[1][0].w;
      const float b6 = A[1][1].x + A[1][1].y, b7 = A[1][1].z + A[1][1].w;
      const float t0 = b0 + b1, t1 = b0 - b1, t2 = b2 + b3, t3 = b2 - b3;
      const float t4 = b4 + b5, t5 = b4 - b5, t6 = b6 + b7, t7 = b6 - b7;
      const float u0 = t0 + t2, u2 = t0 - t2, u1 = t1 + t3, u3 = t1 - t3;
      const float u4 = t4 + t6, u6 = t4 - t6, u5 = t5 + t7, u7 = t5 - t7;
      sk[0] = 0.125f * (u0 + u4);
      sk[4] = 0.125f * (u0 - u4);
      sk[1] = 0.125f * (u1 + u5);
      sk[5] = 0.125f * (u1 - u5);
      sk[2] = 0.125f * (u2 + u6);
      sk[6] = 0.125f * (u2 - u6);
      sk[3] = 0.125f * (u3 + u7);
      sk[7] = 0.125f * (u3 - u7);
    }
    float* o = s + (size_t)inp * IS + (size_t)bc * M3 + v;
#pragma unroll
    for (int k = 0; k < 8; ++k) {
      float2 st;
      st.x = sk0[k];
      st.y = sk1[k];
      *reinterpret_cast<float2*>(o + (size_t)k * KS) = st;
    }
  }
}

// R9 k_mix (proven 62us warm): 512 blocks, scalar voxel axis, XCD-pinned k.
__global__ __launch_bounds__(256) void k_mix(const float* __restrict__ W1,
                                             const float* __restrict__ W2,
                                             const float* __restrict__ s,
                                             float* __restrict__ mixed) {
  const int bid  = blockIdx.x;
  const int k    = bid & 7;
  const int rest = bid >> 3;       // og(4) x vblk(16)
  const int og   = rest & 3;
  const int vblk = rest >> 2;
  const int v = vblk * 256 + threadIdx.x;
  const float* pW1 = W1 + ((size_t)k * 1024 + og * 8) * M3 + v;
  const float* pW2 = W2 + ((size_t)k * 1024 + og * 8) * M3 + v;
  const float* ps  = s + (size_t)k * KS + v;
  float acc[4][8];
#pragma unroll
  for (int b = 0; b < 4; ++b)
#pragma unroll
    for (int oo = 0; oo < 8; ++oo) acc[b][oo] = 0.f;
#pragma unroll 2
  for (int i = 0; i < 32; ++i) {
    float s1b[4], s2b[4];
#pragma unroll
    for (int b = 0; b < 4; ++b) {
      s1b[b] = ps[(size_t)(b * 32 + i) * M3];
      s2b[b] = ps[(size_t)IS + (size_t)(b * 32 + i) * M3];
    }
#pragma unroll
    for (int oo = 0; oo < 8; ++oo) {
      const float w1 = pW1[(size_t)(i * 32 + oo) * M3];
      const float w2 = pW2[(size_t)(i * 32 + oo) * M3];
#pragma unroll
      for (int b = 0; b < 4; ++b) acc[b][oo] += s1b[b] * w1 + s2b[b] * w2;
    }
  }
  float* pm = mixed + (size_t)k * KS + (size_t)og * 8 * M3 + v;
#pragma unroll
  for (int b = 0; b < 4; ++b)
#pragma unroll
    for (int oo = 0; oo < 8; ++oo)
      pm[(size_t)b * (32 * M3) + (size_t)oo * M3] = acc[b][oo];
}

__global__ __launch_bounds__(256) void k_inv(const float* __restrict__ mixed,
                                             float* __restrict__ out) {
  const int tid = blockIdx.x * 256 + threadIdx.x;  // 4*32*4096 threads
  const int v = tid & 4095;
  const int o = (tid >> 12) & 31;
  const int b = tid >> 17;
  const float* pm = mixed + (size_t)(b * 32 + o) * M3 + v;
  const float m0 = pm[0 * (size_t)KS], m1 = pm[1 * (size_t)KS];
  const float m2 = pm[2 * (size_t)KS], m3 = pm[3 * (size_t)KS];
  const float m4 = pm[4 * (size_t)KS], m5 = pm[5 * (size_t)KS];
  const float m6 = pm[6 * (size_t)KS], m7 = pm[7 * (size_t)KS];
  const float t0 = m0 + m1, t1 = m0 - m1, t2 = m2 + m3, t3 = m2 - m3;
  const float t4 = m4 + m5, t5 = m4 - m5, t6 = m6 + m7, t7 = m6 - m7;
  const float u0 = t0 + t2, u2 = t0 - t2, u1 = t1 + t3, u3 = t1 - t3;
  const float u4 = t4 + t6, u6 = t4 - t6, u5 = t5 + t7, u7 = t5 - t7;
  float w[2][2][2];  // w[p][q][r], m = p*4+q*2+r, includes the 1/8
  w[0][0][0] = 0.125f * (u0 + u4);
  w[1][0][0] = 0.125f * (u0 - u4);
  w[0][0][1] = 0.125f * (u1 + u5);
  w[1][0][1] = 0.125f * (u1 - u5);
  w[0][1][0] = 0.125f * (u2 + u6);
  w[1][1][0] = 0.125f * (u2 - u6);
  w[0][1][1] = 0.125f * (u3 + u7);
  w[1][1][1] = 0.125f * (u3 - u7);
  const int z = v & 15, y = (v >> 4) & 15, x = v >> 8;
  float* base =
      out + ((((size_t)(b * 32 + o) * 64 + 4 * x) * 64 + 4 * y) * 64 + 4 * z);
#pragma unroll
  for (int dd = 0; dd < 4; ++dd) {
    const int p = dd >> 1;
#pragma unroll
    for (int hh = 0; hh < 4; ++hh) {
      const int q = hh >> 1;
      const float lo = w[p][q][0], hi = w[p][q][1];
      float4 f;
      f.x = lo; f.y = lo; f.z = hi; f.w = hi;
      *reinterpret_cast<float4*>(base + (dd * 64 + hh) * 64) = f;
    }
  }
}

extern "C" void kernel_launch(void* const* d_in, const int* in_sizes, int n_in,
                              void* d_out, int out_size, void* d_ws, size_t ws_size,
                              hipStream_t stream) {
  const float* x1 = (const float*)d_in[0];
  const float* x2 = (const float*)d_in[1];
  const float* W1 = (const float*)d_in[2];
  const float* W2 = (const float*)d_in[3];
  float* out = (float*)d_out;
  float* s     = (float*)d_ws;             // 2*IS floats = 32 MiB
  float* mixed = s + 2 * (size_t)IS;       // IS floats   = 16 MiB
  k_fwd<<<1024, 256, 0, stream>>>(x1, x2, s);
  k_mix<<<512, 256, 0, stream>>>(W1, W2, s, mixed);
  k_inv<<<2048, 256, 0, stream>>>(mixed, out);
}

// Round 13
// 171.210 us; speedup vs baseline: 1.5378x; 1.0020x over previous
//
#include <hip/hip_runtime.h>

// WaveConv3d: B=4, C=32, D=H=W=64, LEVEL=2, m=16.
// Stage 1: s[inp][k][b][c][v16] = (1/8) * WHT3( 2x2x2 sums of 4x4x4 block )
// Stage 2: mixed[k][b][o][v] = sum_i s1*W1 + s2*W2   (per-voxel 32x32 mixing)
// Stage 3: out = (1/8) * invWHT3(mixed) broadcast to 4x4x4 blocks
//
// R13: warm attribution (R11/R12 algebra + R9 mix measurement):
//   k_fwd(R7)=36, k_mix=62, k_inv=60-65 (vs 23 roofline!), gaps~6.
// k_inv was the hidden pig: its stores are 4x256B scattered segments per
// wave instruction (z*y lane mapping vs 1KB row stride). Rewrite with LDS
// transpose: compute thread=voxel -> w[8] to LDS (pad 10 -> <=2-way reads),
// write phase lanes = consecutive float4 slots -> 1KB contiguous per wave
// per instruction, 64KB contiguous per block. k_fwd reverted to R7 (proven
// 36us; R12's z-pair was +5). k_mix = R9 exact.

#define M3 4096        // 16*16*16 voxels
#define KS 524288      // 4*32*M3  : k-stride in s / mixed
#define IS 4194304     // 8*KS     : input-stride in s

__global__ __launch_bounds__(256) void k_fwd(const float* __restrict__ x1,
                                             const float* __restrict__ x2,
                                             float* __restrict__ s) {
  const int tid = blockIdx.x * 256 + threadIdx.x;   // 2048 blocks
  const int v  = tid & 4095;
  const int bc = tid >> 12;          // 0..127  (b*32+c)
  const int z = v & 15, y = (v >> 4) & 15, x = v >> 8;
  const size_t base = ((((size_t)bc * 64 + 4 * x) * 64 + 4 * y) * 64 + 4 * z);
  // 4 independent address streams: {x1,x2} x {planes dd=0,1 | dd=2,3}
  const float* __restrict__ p10 = x1 + base;
  const float* __restrict__ p11 = x1 + base + 2 * 4096;
  const float* __restrict__ p20 = x2 + base;
  const float* __restrict__ p21 = x2 + base + 2 * 4096;

  float4 a1[2][2], a2[2][2];         // [p][q] float4 partial sums
#pragma unroll
  for (int p = 0; p < 2; ++p)
#pragma unroll
    for (int q = 0; q < 2; ++q) {
      a1[p][q] = make_float4(0.f, 0.f, 0.f, 0.f);
      a2[p][q] = make_float4(0.f, 0.f, 0.f, 0.f);
    }

#pragma unroll
  for (int dp = 0; dp < 2; ++dp) {     // dd within each plane-pair
#pragma unroll
    for (int hh = 0; hh < 4; ++hh) {
      const int off = (dp * 64 + hh) * 64;   // dd*4096 + hh*64
      const float4 f10 = *reinterpret_cast<const float4*>(p10 + off);
      const float4 f20 = *reinterpret_cast<const float4*>(p20 + off);
      const float4 f11 = *reinterpret_cast<const float4*>(p11 + off);
      const float4 f21 = *reinterpret_cast<const float4*>(p21 + off);
      const int q = hh >> 1;
      a1[0][q].x += f10.x; a1[0][q].y += f10.y; a1[0][q].z += f10.z; a1[0][q].w += f10.w;
      a1[1][q].x += f11.x; a1[1][q].y += f11.y; a1[1][q].z += f11.z; a1[1][q].w += f11.w;
      a2[0][q].x += f20.x; a2[0][q].y += f20.y; a2[0][q].z += f20.z; a2[0][q].w += f20.w;
      a2[1][q].x += f21.x; a2[1][q].y += f21.y; a2[1][q].z += f21.z; a2[1][q].w += f21.w;
    }
  }

#pragma unroll
  for (int inp = 0; inp < 2; ++inp) {
    float4 (*A)[2] = inp ? a2 : a1;
    const float b0 = A[0][0].x + A[0][0].y, b1 = A[0][0].z + A[0][0].w;
    const float b2 = A[0][1].x + A[0][1].y, b3 = A[0][1].z + A[0][1].w;
    const float b4 = A[1][0].x + A[1][0].y, b5 = A[1][0].z + A[1][0].w;
    const float b6 = A[1][1].x + A[1][1].y, b7 = A[1][1].z + A[1][1].w;
    const float t0 = b0 + b1, t1 = b0 - b1, t2 = b2 + b3, t3 = b2 - b3;
    const float t4 = b4 + b5, t5 = b4 - b5, t6 = b6 + b7, t7 = b6 - b7;
    const float u0 = t0 + t2, u2 = t0 - t2, u1 = t1 + t3, u3 = t1 - t3;
    const float u4 = t4 + t6, u6 = t4 - t6, u5 = t5 + t7, u7 = t5 - t7;
    float* o = s + (size_t)inp * IS + (size_t)bc * M3 + v;
    o[0 * KS] = 0.125f * (u0 + u4);
    o[4 * KS] = 0.125f * (u0 - u4);
    o[1 * KS] = 0.125f * (u1 + u5);
    o[5 * KS] = 0.125f * (u1 - u5);
    o[2 * KS] = 0.125f * (u2 + u6);
    o[6 * KS] = 0.125f * (u2 - u6);
    o[3 * KS] = 0.125f * (u3 + u7);
    o[7 * KS] = 0.125f * (u3 - u7);
  }
}

// R9 k_mix (proven 62us warm): 512 blocks, scalar voxel axis, XCD-pinned k.
__global__ __launch_bounds__(256) void k_mix(const float* __restrict__ W1,
                                             const float* __restrict__ W2,
                                             const float* __restrict__ s,
                                             float* __restrict__ mixed) {
  const int bid  = blockIdx.x;
  const int k    = bid & 7;
  const int rest = bid >> 3;       // og(4) x vblk(16)
  const int og   = rest & 3;
  const int vblk = rest >> 2;
  const int v = vblk * 256 + threadIdx.x;
  const float* pW1 = W1 + ((size_t)k * 1024 + og * 8) * M3 + v;
  const float* pW2 = W2 + ((size_t)k * 1024 + og * 8) * M3 + v;
  const float* ps  = s + (size_t)k * KS + v;
  float acc[4][8];
#pragma unroll
  for (int b = 0; b < 4; ++b)
#pragma unroll
    for (int oo = 0; oo < 8; ++oo) acc[b][oo] = 0.f;
#pragma unroll 2
  for (int i = 0; i < 32; ++i) {
    float s1b[4], s2b[4];
#pragma unroll
    for (int b = 0; b < 4; ++b) {
      s1b[b] = ps[(size_t)(b * 32 + i) * M3];
      s2b[b] = ps[(size_t)IS + (size_t)(b * 32 + i) * M3];
    }
#pragma unroll
    for (int oo = 0; oo < 8; ++oo) {
      const float w1 = pW1[(size_t)(i * 32 + oo) * M3];
      const float w2 = pW2[(size_t)(i * 32 + oo) * M3];
#pragma unroll
      for (int b = 0; b < 4; ++b) acc[b][oo] += s1b[b] * w1 + s2b[b] * w2;
    }
  }
  float* pm = mixed + (size_t)k * KS + (size_t)og * 8 * M3 + v;
#pragma unroll
  for (int b = 0; b < 4; ++b)
#pragma unroll
    for (int oo = 0; oo < 8; ++oo)
      pm[(size_t)b * (32 * M3) + (size_t)oo * M3] = acc[b][oo];
}

// R13 k_inv: LDS-transposed stores. Block = (bc, x-slab): 2048 blocks x 256.
// Compute: thread=voxel (y,z): 8 strided mixed reads (L2/L3), 8-pt WHT,
// w[8] -> LDS (pad 10). Write: thread j-loop over 16 consecutive-f4 slots;
// each store instr = 1KB contiguous per wave (4KB per 256 threads); block
// writes 64KB contiguous. b64 LDS readback, <=2-way bank aliasing.
__global__ __launch_bounds__(256) void k_inv(const float* __restrict__ mixed,
                                             float* __restrict__ out) {
  const int bid = blockIdx.x;          // bc*16 + x
  const int x   = bid & 15;
  const int bc  = bid >> 4;
  const int tid = threadIdx.x;         // voxel y*16+z
  __shared__ float wlds[256 * 10];     // 10 KB, pad 10

  const int v = x * 256 + tid;
  const float* pm = mixed + (size_t)bc * M3 + v;
  const float m0 = pm[0 * (size_t)KS], m1 = pm[1 * (size_t)KS];
  const float m2 = pm[2 * (size_t)KS], m3 = pm[3 * (size_t)KS];
  const float m4 = pm[4 * (size_t)KS], m5 = pm[5 * (size_t)KS];
  const float m6 = pm[6 * (size_t)KS], m7 = pm[7 * (size_t)KS];
  const float t0 = m0 + m1, t1 = m0 - m1, t2 = m2 + m3, t3 = m2 - m3;
  const float t4 = m4 + m5, t5 = m4 - m5, t6 = m6 + m7, t7 = m6 - m7;
  const float u0 = t0 + t2, u2 = t0 - t2, u1 = t1 + t3, u3 = t1 - t3;
  const float u4 = t4 + t6, u6 = t4 - t6, u5 = t5 + t7, u7 = t5 - t7;
  float* wl = &wlds[tid * 10];         // [p*4 + q*2 + r]
  wl[0] = 0.125f * (u0 + u4);          // p0 q0 r0
  wl[4] = 0.125f * (u0 - u4);          // p1 q0 r0
  wl[1] = 0.125f * (u1 + u5);          // p0 q0 r1
  wl[5] = 0.125f * (u1 - u5);          // p1 q0 r1
  wl[2] = 0.125f * (u2 + u6);          // p0 q1 r0
  wl[6] = 0.125f * (u2 - u6);          // p1 q1 r0
  wl[3] = 0.125f * (u3 + u7);          // p0 q1 r1
  wl[7] = 0.125f * (u3 - u7);          // p1 q1 r1
  __syncthreads();

  float4* ob = reinterpret_cast<float4*>(out) + (size_t)bc * 65536 + (size_t)x * 4096;
#pragma unroll
  for (int j = 0; j < 16; ++j) {
    const int sIdx = j * 256 + tid;    // float4 slot in the 64KB block region
    const int dd  = sIdx >> 10;        // d-offset 0..3 (p = dd>>1)
    const int row = (sIdx >> 4) & 63;  // h-row: 4*yv + 2*q + f
    const int zv  = sIdx & 15;         // z voxel
    const int yv  = row >> 2;
    const int q   = (row & 3) >> 1;
    const float2 wr = *reinterpret_cast<const float2*>(
        &wlds[(yv * 16 + zv) * 10 + ((dd >> 1) * 4 + q * 2)]);
    float4 f;
    f.x = wr.x; f.y = wr.x; f.z = wr.y; f.w = wr.y;
    ob[sIdx] = f;
  }
}

extern "C" void kernel_launch(void* const* d_in, const int* in_sizes, int n_in,
                              void* d_out, int out_size, void* d_ws, size_t ws_size,
                              hipStream_t stream) {
  const float* x1 = (const float*)d_in[0];
  const float* x2 = (const float*)d_in[1];
  const float* W1 = (const float*)d_in[2];
  const float* W2 = (const float*)d_in[3];
  float* out = (float*)d_out;
  float* s     = (float*)d_ws;             // 2*IS floats = 32 MiB
  float* mixed = s + 2 * (size_t)IS;       // IS floats   = 16 MiB
  k_fwd<<<2048, 256, 0, stream>>>(x1, x2, s);
  k_mix<<<512, 256, 0, stream>>>(W1, W2, s, mixed);
  k_inv<<<2048, 256, 0, stream>>>(mixed, out);
}